// Round 1
// baseline (1079.442 us; speedup 1.0000x reference)
//
#include <hip/hip_runtime.h>

#define NN 10000      // nodes
#define NE 160000     // edges
#define HF 512        // hidden/in features
#define LL 6          // layers
#define NC 64         // classes
#define KCAT (LL*HF)  // 3072
#define BN_EPS 1e-5f

// ---------------- setup kernels ----------------

__global__ void zero_u32_kernel(unsigned* __restrict__ p, int n) {
  int i = blockIdx.x * blockDim.x + threadIdx.x;
  if (i < n) p[i] = 0u;
}

__global__ void deg_kernel(const int* __restrict__ src, const int* __restrict__ dst,
                           unsigned* __restrict__ cnt_out, unsigned* __restrict__ cnt_in) {
  int e = blockIdx.x * blockDim.x + threadIdx.x;
  if (e < NE) {
    atomicAdd(&cnt_out[src[e]], 1u);
    atomicAdd(&cnt_in[dst[e]], 1u);
  }
}

__global__ void norm_kernel(const unsigned* __restrict__ cnt_out, const unsigned* __restrict__ cnt_in,
                            float* __restrict__ norm_src, float* __restrict__ norm_dst) {
  int i = blockIdx.x * blockDim.x + threadIdx.x;
  if (i < NN) {
    unsigned co = cnt_out[i]; if (co < 1u) co = 1u;
    unsigned ci = cnt_in[i];  if (ci < 1u) ci = 1u;
    norm_src[i] = rsqrtf((float)co);
    norm_dst[i] = rsqrtf((float)ci);
  }
}

// exclusive scan of cnt[0..NN) -> off[0..NN], single block of 1024
__global__ void scan_kernel(const unsigned* __restrict__ cnt, unsigned* __restrict__ off) {
  __shared__ unsigned wsum[16];
  int tid = threadIdx.x;
  int lane = tid & 63, wid = tid >> 6;
  unsigned base = 0;
  for (int c = 0; c < NN; c += 1024) {
    int i = c + tid;
    unsigned v = (i < NN) ? cnt[i] : 0u;
    unsigned x = v;
    #pragma unroll
    for (int d = 1; d < 64; d <<= 1) {
      unsigned y = __shfl_up(x, d, 64);
      if (lane >= d) x += y;
    }
    if (lane == 63) wsum[wid] = x;
    __syncthreads();
    if (wid == 0 && lane < 16) {
      unsigned s = wsum[lane];
      #pragma unroll
      for (int d = 1; d < 16; d <<= 1) {
        unsigned y = __shfl_up(s, d, 16);
        if (lane >= d) s += y;
      }
      wsum[lane] = s;
    }
    __syncthreads();
    unsigned wbase = wid ? wsum[wid - 1] : 0u;
    if (i < NN) off[i] = base + wbase + x - v;
    unsigned tot = wsum[15];
    __syncthreads();
    base += tot;
  }
  if (tid == 0) off[NN] = base;
}

__global__ void fill_kernel(const int* __restrict__ src, const int* __restrict__ dst,
                            const unsigned* __restrict__ off, unsigned* __restrict__ cursor,
                            int* __restrict__ edge_src) {
  int e = blockIdx.x * blockDim.x + threadIdx.x;
  if (e < NE) {
    int d = dst[e];
    unsigned p = atomicAdd(&cursor[d], 1u);
    edge_src[off[d] + p] = src[e];
  }
}

// ---------------- layer GEMM: m = (A ⊙ norm_src) @ W ----------------
// BM=128, BN=128, BK=16; 256 threads, 8x8 per thread. N dim = 512 (grid.x=4).
__launch_bounds__(256)
__global__ void gemm_layer(const float* __restrict__ A, int lda,
                           const float* __restrict__ W,
                           const float* __restrict__ norm_src,
                           float* __restrict__ Mout) {
  __shared__ float As[16][128];
  __shared__ float Bs[16][128];
  int tid = threadIdx.x;
  int m0 = blockIdx.y * 128;
  int n0 = blockIdx.x * 128;
  int tx = tid & 15, ty = tid >> 4;
  float acc[8][8];
  #pragma unroll
  for (int i = 0; i < 8; ++i)
    #pragma unroll
    for (int j = 0; j < 8; ++j) acc[i][j] = 0.f;

  for (int k0 = 0; k0 < HF; k0 += 16) {
    __syncthreads();
    // A tile: 128 rows x 16 k, transposed into As[k][row], scaled by norm_src
    #pragma unroll
    for (int p = 0; p < 2; ++p) {
      int idx = p * 256 + tid;
      int arow = idx >> 2;       // 0..127
      int akq  = idx & 3;        // 0..3  (float4 along k)
      int r = m0 + arow;
      float4 v = make_float4(0.f, 0.f, 0.f, 0.f);
      float ns = 0.f;
      if (r < NN) {
        v = *(const float4*)&A[(size_t)r * lda + k0 + akq * 4];
        ns = norm_src[r];
      }
      As[akq * 4 + 0][arow] = v.x * ns;
      As[akq * 4 + 1][arow] = v.y * ns;
      As[akq * 4 + 2][arow] = v.z * ns;
      As[akq * 4 + 3][arow] = v.w * ns;
    }
    // B tile: 16 k x 128 n
    #pragma unroll
    for (int p = 0; p < 2; ++p) {
      int idx = p * 256 + tid;
      int bk = idx >> 5;         // 0..15
      int bq = idx & 31;         // 0..31
      *(float4*)&Bs[bk][bq * 4] =
          *(const float4*)&W[(size_t)(k0 + bk) * HF + n0 + bq * 4];
    }
    __syncthreads();
    #pragma unroll
    for (int k = 0; k < 16; ++k) {
      float a[8], b[8];
      *(float4*)&a[0] = *(const float4*)&As[k][ty * 8];
      *(float4*)&a[4] = *(const float4*)&As[k][ty * 8 + 4];
      *(float4*)&b[0] = *(const float4*)&Bs[k][tx * 8];
      *(float4*)&b[4] = *(const float4*)&Bs[k][tx * 8 + 4];
      #pragma unroll
      for (int i = 0; i < 8; ++i)
        #pragma unroll
        for (int j = 0; j < 8; ++j)
          acc[i][j] = fmaf(a[i], b[j], acc[i][j]);
    }
  }
  #pragma unroll
  for (int i = 0; i < 8; ++i) {
    int r = m0 + ty * 8 + i;
    if (r < NN) {
      float4 v0 = make_float4(acc[i][0], acc[i][1], acc[i][2], acc[i][3]);
      float4 v1 = make_float4(acc[i][4], acc[i][5], acc[i][6], acc[i][7]);
      *(float4*)&Mout[(size_t)r * HF + n0 + tx * 8]     = v0;
      *(float4*)&Mout[(size_t)r * HF + n0 + tx * 8 + 4] = v1;
    }
  }
}

// ---------------- aggregation + norm_dst + bias + BN + ReLU ----------------
// one block (128 threads) per dst node; each thread owns 4 consecutive features
__launch_bounds__(128)
__global__ void agg_bn_kernel(const float* __restrict__ Mm,
                              const int* __restrict__ edge_src,
                              const unsigned* __restrict__ row_off,
                              const float* __restrict__ norm_dst,
                              const float* __restrict__ bias,
                              const float* __restrict__ gamma,
                              const float* __restrict__ beta,
                              const float* __restrict__ mean,
                              const float* __restrict__ var,
                              float* __restrict__ hcat_col) {  // hcat + l*HF, row stride KCAT
  int n = blockIdx.x;
  int f = threadIdx.x * 4;
  unsigned e0 = row_off[n], e1 = row_off[n + 1];
  float ax = 0.f, ay = 0.f, az = 0.f, aw = 0.f;
  for (unsigned e = e0; e < e1; ++e) {
    int s = edge_src[e];
    float4 v = *(const float4*)&Mm[(size_t)s * HF + f];
    ax += v.x; ay += v.y; az += v.z; aw += v.w;
  }
  float nd = norm_dst[n];
  float4 b  = *(const float4*)&bias[f];
  float4 g  = *(const float4*)&gamma[f];
  float4 bt = *(const float4*)&beta[f];
  float4 mu = *(const float4*)&mean[f];
  float4 vr = *(const float4*)&var[f];
  float sx = g.x * rsqrtf(vr.x + BN_EPS);
  float sy = g.y * rsqrtf(vr.y + BN_EPS);
  float sz = g.z * rsqrtf(vr.z + BN_EPS);
  float sw = g.w * rsqrtf(vr.w + BN_EPS);
  float yx = (ax * nd + b.x - mu.x) * sx + bt.x;
  float yy = (ay * nd + b.y - mu.y) * sy + bt.y;
  float yz = (az * nd + b.z - mu.z) * sz + bt.z;
  float yw = (aw * nd + b.w - mu.w) * sw + bt.w;
  float4 y = make_float4(fmaxf(yx, 0.f), fmaxf(yy, 0.f), fmaxf(yz, 0.f), fmaxf(yw, 0.f));
  *(float4*)&hcat_col[(size_t)n * KCAT + f] = y;
}

// ---------------- final GEMM: out = hcat @ linW + linb ----------------
// BM=64, BN=64, BK=32; 256 threads, 4x4 per thread
__launch_bounds__(256)
__global__ void final_gemm(const float* __restrict__ hcat,
                           const float* __restrict__ linW,   // [3072][64]
                           const float* __restrict__ linb,
                           float* __restrict__ out) {
  __shared__ float As[32][64];
  __shared__ float Bs[32][64];
  int tid = threadIdx.x;
  int m0 = blockIdx.x * 64;
  int tx = tid & 15, ty = tid >> 4;
  float acc[4][4];
  #pragma unroll
  for (int i = 0; i < 4; ++i)
    #pragma unroll
    for (int j = 0; j < 4; ++j) acc[i][j] = 0.f;

  for (int k0 = 0; k0 < KCAT; k0 += 32) {
    __syncthreads();
    // A tile: 64 rows x 32 k -> As[k][row]
    #pragma unroll
    for (int p = 0; p < 2; ++p) {
      int idx = p * 256 + tid;
      int arow = idx >> 3;      // 0..63
      int akq  = idx & 7;       // 0..7
      int r = m0 + arow;
      float4 v = make_float4(0.f, 0.f, 0.f, 0.f);
      if (r < NN) v = *(const float4*)&hcat[(size_t)r * KCAT + k0 + akq * 4];
      As[akq * 4 + 0][arow] = v.x;
      As[akq * 4 + 1][arow] = v.y;
      As[akq * 4 + 2][arow] = v.z;
      As[akq * 4 + 3][arow] = v.w;
    }
    // B tile: 32 k x 64 n
    #pragma unroll
    for (int p = 0; p < 2; ++p) {
      int idx = p * 256 + tid;
      int bk = idx >> 4;        // 0..31
      int bq = idx & 15;        // 0..15
      *(float4*)&Bs[bk][bq * 4] = *(const float4*)&linW[(size_t)(k0 + bk) * NC + bq * 4];
    }
    __syncthreads();
    #pragma unroll
    for (int k = 0; k < 32; ++k) {
      float a[4], b[4];
      *(float4*)&a[0] = *(const float4*)&As[k][ty * 4];
      *(float4*)&b[0] = *(const float4*)&Bs[k][tx * 4];
      #pragma unroll
      for (int i = 0; i < 4; ++i)
        #pragma unroll
        for (int j = 0; j < 4; ++j)
          acc[i][j] = fmaf(a[i], b[j], acc[i][j]);
    }
  }
  float4 bb = *(const float4*)&linb[tx * 4];
  #pragma unroll
  for (int i = 0; i < 4; ++i) {
    int r = m0 + ty * 4 + i;
    if (r < NN) {
      float4 v = make_float4(acc[i][0] + bb.x, acc[i][1] + bb.y,
                             acc[i][2] + bb.z, acc[i][3] + bb.w);
      *(float4*)&out[(size_t)r * NC + tx * 4] = v;
    }
  }
}

// ---------------- launch ----------------

extern "C" void kernel_launch(void* const* d_in, const int* in_sizes, int n_in,
                              void* d_out, int out_size, void* d_ws, size_t ws_size,
                              hipStream_t stream) {
  const float* x     = (const float*)d_in[0];
  const float* W0    = (const float*)d_in[1];
  const float* Ws    = (const float*)d_in[2];
  const float* bs    = (const float*)d_in[3];
  const float* gamma = (const float*)d_in[4];
  const float* beta  = (const float*)d_in[5];
  const float* rmean = (const float*)d_in[6];
  const float* rvar  = (const float*)d_in[7];
  const float* linW  = (const float*)d_in[8];
  const float* linb  = (const float*)d_in[9];
  const int*   src   = (const int*)d_in[10];
  const int*   dst   = (const int*)d_in[11];
  float* out = (float*)d_out;

  char* w = (char*)d_ws;
  size_t o = 0;
  auto carve = [&](size_t bytes) -> void* {
    o = (o + 255) & ~(size_t)255;
    void* p = w + o;
    o += bytes;
    return p;
  };
  float*    m_buf = (float*)carve((size_t)NN * HF * 4);
  float*    hcat  = (float*)carve((size_t)NN * KCAT * 4);
  float*    nsrc  = (float*)carve((size_t)NN * 4);
  float*    ndst  = (float*)carve((size_t)NN * 4);
  unsigned* cnts  = (unsigned*)carve((size_t)3 * NN * 4);  // cnt_out, cnt_in, cursor
  unsigned* roff  = (unsigned*)carve((size_t)(NN + 1) * 4);
  int*      esrc  = (int*)carve((size_t)NE * 4);

  unsigned* cnt_out = cnts;
  unsigned* cnt_in  = cnts + NN;
  unsigned* cursor  = cnts + 2 * NN;

  zero_u32_kernel<<<(3 * NN + 255) / 256, 256, 0, stream>>>(cnts, 3 * NN);
  deg_kernel<<<(NE + 255) / 256, 256, 0, stream>>>(src, dst, cnt_out, cnt_in);
  norm_kernel<<<(NN + 255) / 256, 256, 0, stream>>>(cnt_out, cnt_in, nsrc, ndst);
  scan_kernel<<<1, 1024, 0, stream>>>(cnt_in, roff);
  fill_kernel<<<(NE + 255) / 256, 256, 0, stream>>>(src, dst, roff, cursor, esrc);

  for (int l = 0; l < LL; ++l) {
    const float* A   = (l == 0) ? x : (hcat + (size_t)(l - 1) * HF);
    int          lda = (l == 0) ? HF : KCAT;
    const float* Wl  = (l == 0) ? W0 : (Ws + (size_t)(l - 1) * HF * HF);
    gemm_layer<<<dim3(HF / 128, (NN + 127) / 128), 256, 0, stream>>>(A, lda, Wl, nsrc, m_buf);
    agg_bn_kernel<<<NN, 128, 0, stream>>>(m_buf, esrc, roff, ndst,
                                          bs + l * HF, gamma + l * HF, beta + l * HF,
                                          rmean + l * HF, rvar + l * HF,
                                          hcat + (size_t)l * HF);
  }
  final_gemm<<<(NN + 63) / 64, 256, 0, stream>>>(hcat, linW, linb, out);
}

// Round 2
// 814.041 us; speedup vs baseline: 1.3260x; 1.3260x over previous
//
#include <hip/hip_runtime.h>

#define NN 10000      // nodes
#define NE 160000     // edges
#define HF 512        // hidden/in features
#define LL 6          // layers
#define NC 64         // classes
#define KCAT (LL*HF)  // 3072
#define BN_EPS 1e-5f

// ---------------- setup kernels ----------------

__global__ void zero_u32_kernel(unsigned* __restrict__ p, int n) {
  int i = blockIdx.x * blockDim.x + threadIdx.x;
  if (i < n) p[i] = 0u;
}

__global__ void deg_kernel(const int* __restrict__ src, const int* __restrict__ dst,
                           unsigned* __restrict__ cnt_out, unsigned* __restrict__ cnt_in) {
  int e = blockIdx.x * blockDim.x + threadIdx.x;
  if (e < NE) {
    atomicAdd(&cnt_out[src[e]], 1u);
    atomicAdd(&cnt_in[dst[e]], 1u);
  }
}

__global__ void norm_kernel(const unsigned* __restrict__ cnt_out, const unsigned* __restrict__ cnt_in,
                            float* __restrict__ norm_src, float* __restrict__ norm_dst) {
  int i = blockIdx.x * blockDim.x + threadIdx.x;
  if (i < NN) {
    unsigned co = cnt_out[i]; if (co < 1u) co = 1u;
    unsigned ci = cnt_in[i];  if (ci < 1u) ci = 1u;
    norm_src[i] = rsqrtf((float)co);
    norm_dst[i] = rsqrtf((float)ci);
  }
}

// exclusive scan of cnt[0..NN) -> off[0..NN], single block of 1024
__global__ void scan_kernel(const unsigned* __restrict__ cnt, unsigned* __restrict__ off) {
  __shared__ unsigned wsum[16];
  int tid = threadIdx.x;
  int lane = tid & 63, wid = tid >> 6;
  unsigned base = 0;
  for (int c = 0; c < NN; c += 1024) {
    int i = c + tid;
    unsigned v = (i < NN) ? cnt[i] : 0u;
    unsigned x = v;
    #pragma unroll
    for (int d = 1; d < 64; d <<= 1) {
      unsigned y = __shfl_up(x, d, 64);
      if (lane >= d) x += y;
    }
    if (lane == 63) wsum[wid] = x;
    __syncthreads();
    if (wid == 0 && lane < 16) {
      unsigned s = wsum[lane];
      #pragma unroll
      for (int d = 1; d < 16; d <<= 1) {
        unsigned y = __shfl_up(s, d, 16);
        if (lane >= d) s += y;
      }
      wsum[lane] = s;
    }
    __syncthreads();
    unsigned wbase = wid ? wsum[wid - 1] : 0u;
    if (i < NN) off[i] = base + wbase + x - v;
    unsigned tot = wsum[15];
    __syncthreads();
    base += tot;
  }
  if (tid == 0) off[NN] = base;
}

__global__ void fill_kernel(const int* __restrict__ src, const int* __restrict__ dst,
                            const unsigned* __restrict__ off, unsigned* __restrict__ cursor,
                            int* __restrict__ edge_src) {
  int e = blockIdx.x * blockDim.x + threadIdx.x;
  if (e < NE) {
    int d = dst[e];
    unsigned p = atomicAdd(&cursor[d], 1u);
    edge_src[off[d] + p] = src[e];
  }
}

// ---------------- layer GEMM: m = (A ⊙ norm_src) @ W ----------------
// BM=64, BN=128, BK=32; 256 threads, 4x8 per thread; grid (4, 157) = 628 blocks.
// As padded to stride 68 (transpose-scatter writes 2-way instead of 8-way).
// B fragment read as two half-tiles at tx*4 (2-way = free, vs 4-way at tx*8).
__launch_bounds__(256)
__global__ void gemm_layer(const float* __restrict__ A, int lda,
                           const float* __restrict__ W,
                           const float* __restrict__ norm_src,
                           float* __restrict__ Mout) {
  __shared__ float As[32][68];
  __shared__ float Bs[32][128];
  int tid = threadIdx.x;
  int m0 = blockIdx.y * 64;
  int n0 = blockIdx.x * 128;
  int tx = tid & 15, ty = tid >> 4;
  float acc[4][8];
  #pragma unroll
  for (int i = 0; i < 4; ++i)
    #pragma unroll
    for (int j = 0; j < 8; ++j) acc[i][j] = 0.f;

  for (int k0 = 0; k0 < HF; k0 += 32) {
    __syncthreads();
    // A tile: 64 rows x 32 k, transposed into As[k][row], scaled by norm_src
    #pragma unroll
    for (int p = 0; p < 2; ++p) {
      int idx = p * 256 + tid;
      int arow = idx >> 3;       // 0..63
      int akq  = idx & 7;        // 0..7  (float4 along k)
      int r = m0 + arow;
      float4 v = make_float4(0.f, 0.f, 0.f, 0.f);
      float ns = 0.f;
      if (r < NN) {
        v = *(const float4*)&A[(size_t)r * lda + k0 + akq * 4];
        ns = norm_src[r];
      }
      As[akq * 4 + 0][arow] = v.x * ns;
      As[akq * 4 + 1][arow] = v.y * ns;
      As[akq * 4 + 2][arow] = v.z * ns;
      As[akq * 4 + 3][arow] = v.w * ns;
    }
    // B tile: 32 k x 128 n
    #pragma unroll
    for (int p = 0; p < 4; ++p) {
      int idx = p * 256 + tid;
      int bk = idx >> 5;         // 0..31
      int bq = idx & 31;         // 0..31
      *(float4*)&Bs[bk][bq * 4] =
          *(const float4*)&W[(size_t)(k0 + bk) * HF + n0 + bq * 4];
    }
    __syncthreads();
    #pragma unroll
    for (int k = 0; k < 32; ++k) {
      float a[4], b[8];
      *(float4*)&a[0] = *(const float4*)&As[k][ty * 4];
      *(float4*)&b[0] = *(const float4*)&Bs[k][tx * 4];
      *(float4*)&b[4] = *(const float4*)&Bs[k][64 + tx * 4];
      #pragma unroll
      for (int i = 0; i < 4; ++i)
        #pragma unroll
        for (int j = 0; j < 8; ++j)
          acc[i][j] = fmaf(a[i], b[j], acc[i][j]);
    }
  }
  #pragma unroll
  for (int i = 0; i < 4; ++i) {
    int r = m0 + ty * 4 + i;
    if (r < NN) {
      *(float4*)&Mout[(size_t)r * HF + n0 + tx * 4] =
          make_float4(acc[i][0], acc[i][1], acc[i][2], acc[i][3]);
      *(float4*)&Mout[(size_t)r * HF + n0 + 64 + tx * 4] =
          make_float4(acc[i][4], acc[i][5], acc[i][6], acc[i][7]);
    }
  }
}

// ---------------- aggregation + norm_dst + bias + BN + ReLU ----------------
// one block (128 threads) per dst node; each thread owns 4 consecutive features.
// 4-deep edge unroll: 4 outstanding row loads instead of a 1-deep dependent chain.
__launch_bounds__(128)
__global__ void agg_bn_kernel(const float* __restrict__ Mm,
                              const int* __restrict__ edge_src,
                              const unsigned* __restrict__ row_off,
                              const float* __restrict__ norm_dst,
                              const float* __restrict__ bias,
                              const float* __restrict__ gamma,
                              const float* __restrict__ beta,
                              const float* __restrict__ mean,
                              const float* __restrict__ var,
                              float* __restrict__ hcat_col) {  // hcat + l*HF, row stride KCAT
  int n = blockIdx.x;
  int f = threadIdx.x * 4;
  unsigned e0 = row_off[n], e1 = row_off[n + 1];
  float ax = 0.f, ay = 0.f, az = 0.f, aw = 0.f;
  unsigned e = e0;
  for (; e + 4 <= e1; e += 4) {
    int s0 = edge_src[e], s1 = edge_src[e + 1], s2 = edge_src[e + 2], s3 = edge_src[e + 3];
    float4 v0 = *(const float4*)&Mm[(size_t)s0 * HF + f];
    float4 v1 = *(const float4*)&Mm[(size_t)s1 * HF + f];
    float4 v2 = *(const float4*)&Mm[(size_t)s2 * HF + f];
    float4 v3 = *(const float4*)&Mm[(size_t)s3 * HF + f];
    ax += v0.x + v1.x + v2.x + v3.x;
    ay += v0.y + v1.y + v2.y + v3.y;
    az += v0.z + v1.z + v2.z + v3.z;
    aw += v0.w + v1.w + v2.w + v3.w;
  }
  for (; e < e1; ++e) {
    int s = edge_src[e];
    float4 v = *(const float4*)&Mm[(size_t)s * HF + f];
    ax += v.x; ay += v.y; az += v.z; aw += v.w;
  }
  float nd = norm_dst[n];
  float4 b  = *(const float4*)&bias[f];
  float4 g  = *(const float4*)&gamma[f];
  float4 bt = *(const float4*)&beta[f];
  float4 mu = *(const float4*)&mean[f];
  float4 vr = *(const float4*)&var[f];
  float sx = g.x * rsqrtf(vr.x + BN_EPS);
  float sy = g.y * rsqrtf(vr.y + BN_EPS);
  float sz = g.z * rsqrtf(vr.z + BN_EPS);
  float sw = g.w * rsqrtf(vr.w + BN_EPS);
  float yx = (ax * nd + b.x - mu.x) * sx + bt.x;
  float yy = (ay * nd + b.y - mu.y) * sy + bt.y;
  float yz = (az * nd + b.z - mu.z) * sz + bt.z;
  float yw = (aw * nd + b.w - mu.w) * sw + bt.w;
  float4 y = make_float4(fmaxf(yx, 0.f), fmaxf(yy, 0.f), fmaxf(yz, 0.f), fmaxf(yw, 0.f));
  *(float4*)&hcat_col[(size_t)n * KCAT + f] = y;
}

// ---------------- final GEMM, split-K: part[sp] = hcat[:, sp*512:(sp+1)*512] @ linW[sp*512:...] ----------------
// BM=64, BN=64(=NC), BK=32; 256 threads, 4x4 per thread; grid (157, 6) = 942 blocks.
__launch_bounds__(256)
__global__ void final_gemm_split(const float* __restrict__ hcat,
                                 const float* __restrict__ linW,   // [3072][64]
                                 float* __restrict__ part) {       // [6][NN][64]
  __shared__ float As[32][68];
  __shared__ float Bs[32][64];
  int tid = threadIdx.x;
  int m0 = blockIdx.x * 64;
  int sp = blockIdx.y;
  int kbase = sp * HF;
  int tx = tid & 15, ty = tid >> 4;
  float acc[4][4];
  #pragma unroll
  for (int i = 0; i < 4; ++i)
    #pragma unroll
    for (int j = 0; j < 4; ++j) acc[i][j] = 0.f;

  for (int kk = 0; kk < HF; kk += 32) {
    int k0 = kbase + kk;
    __syncthreads();
    // A tile: 64 rows x 32 k -> As[k][row] (padded stride 68)
    #pragma unroll
    for (int p = 0; p < 2; ++p) {
      int idx = p * 256 + tid;
      int arow = idx >> 3;      // 0..63
      int akq  = idx & 7;       // 0..7
      int r = m0 + arow;
      float4 v = make_float4(0.f, 0.f, 0.f, 0.f);
      if (r < NN) v = *(const float4*)&hcat[(size_t)r * KCAT + k0 + akq * 4];
      As[akq * 4 + 0][arow] = v.x;
      As[akq * 4 + 1][arow] = v.y;
      As[akq * 4 + 2][arow] = v.z;
      As[akq * 4 + 3][arow] = v.w;
    }
    // B tile: 32 k x 64 n
    #pragma unroll
    for (int p = 0; p < 2; ++p) {
      int idx = p * 256 + tid;
      int bk = idx >> 4;        // 0..31
      int bq = idx & 15;        // 0..15
      *(float4*)&Bs[bk][bq * 4] = *(const float4*)&linW[(size_t)(k0 + bk) * NC + bq * 4];
    }
    __syncthreads();
    #pragma unroll
    for (int k = 0; k < 32; ++k) {
      float a[4], b[4];
      *(float4*)&a[0] = *(const float4*)&As[k][ty * 4];
      *(float4*)&b[0] = *(const float4*)&Bs[k][tx * 4];
      #pragma unroll
      for (int i = 0; i < 4; ++i)
        #pragma unroll
        for (int j = 0; j < 4; ++j)
          acc[i][j] = fmaf(a[i], b[j], acc[i][j]);
    }
  }
  #pragma unroll
  for (int i = 0; i < 4; ++i) {
    int r = m0 + ty * 4 + i;
    if (r < NN) {
      *(float4*)&part[((size_t)sp * NN + r) * NC + tx * 4] =
          make_float4(acc[i][0], acc[i][1], acc[i][2], acc[i][3]);
    }
  }
}

// out[n][c] = sum_sp part[sp][n][c] + linb[c]; one float4 per thread
__launch_bounds__(256)
__global__ void final_reduce(const float* __restrict__ part,
                             const float* __restrict__ linb,
                             float* __restrict__ out) {
  int i = blockIdx.x * blockDim.x + threadIdx.x;   // float4 index
  if (i >= NN * NC / 4) return;
  int n  = i >> 4;        // NC/4 = 16 float4 per row
  int cq = i & 15;
  float4 s = *(const float4*)&linb[cq * 4];
  #pragma unroll
  for (int sp = 0; sp < LL; ++sp) {
    float4 v = *(const float4*)&part[((size_t)sp * NN + n) * NC + cq * 4];
    s.x += v.x; s.y += v.y; s.z += v.z; s.w += v.w;
  }
  *(float4*)&out[(size_t)n * NC + cq * 4] = s;
}

// ---------------- launch ----------------

extern "C" void kernel_launch(void* const* d_in, const int* in_sizes, int n_in,
                              void* d_out, int out_size, void* d_ws, size_t ws_size,
                              hipStream_t stream) {
  const float* x     = (const float*)d_in[0];
  const float* W0    = (const float*)d_in[1];
  const float* Ws    = (const float*)d_in[2];
  const float* bs    = (const float*)d_in[3];
  const float* gamma = (const float*)d_in[4];
  const float* beta  = (const float*)d_in[5];
  const float* rmean = (const float*)d_in[6];
  const float* rvar  = (const float*)d_in[7];
  const float* linW  = (const float*)d_in[8];
  const float* linb  = (const float*)d_in[9];
  const int*   src   = (const int*)d_in[10];
  const int*   dst   = (const int*)d_in[11];
  float* out = (float*)d_out;

  char* w = (char*)d_ws;
  size_t o = 0;
  auto carve = [&](size_t bytes) -> void* {
    o = (o + 255) & ~(size_t)255;
    void* p = w + o;
    o += bytes;
    return p;
  };
  float*    m_buf = (float*)carve((size_t)NN * HF * 4);
  float*    hcat  = (float*)carve((size_t)NN * KCAT * 4);
  float*    part  = (float*)carve((size_t)LL * NN * NC * 4);
  float*    nsrc  = (float*)carve((size_t)NN * 4);
  float*    ndst  = (float*)carve((size_t)NN * 4);
  unsigned* cnts  = (unsigned*)carve((size_t)3 * NN * 4);  // cnt_out, cnt_in, cursor
  unsigned* roff  = (unsigned*)carve((size_t)(NN + 1) * 4);
  int*      esrc  = (int*)carve((size_t)NE * 4);

  unsigned* cnt_out = cnts;
  unsigned* cnt_in  = cnts + NN;
  unsigned* cursor  = cnts + 2 * NN;

  zero_u32_kernel<<<(3 * NN + 255) / 256, 256, 0, stream>>>(cnts, 3 * NN);
  deg_kernel<<<(NE + 255) / 256, 256, 0, stream>>>(src, dst, cnt_out, cnt_in);
  norm_kernel<<<(NN + 255) / 256, 256, 0, stream>>>(cnt_out, cnt_in, nsrc, ndst);
  scan_kernel<<<1, 1024, 0, stream>>>(cnt_in, roff);
  fill_kernel<<<(NE + 255) / 256, 256, 0, stream>>>(src, dst, roff, cursor, esrc);

  for (int l = 0; l < LL; ++l) {
    const float* A   = (l == 0) ? x : (hcat + (size_t)(l - 1) * HF);
    int          lda = (l == 0) ? HF : KCAT;
    const float* Wl  = (l == 0) ? W0 : (Ws + (size_t)(l - 1) * HF * HF);
    gemm_layer<<<dim3(HF / 128, (NN + 63) / 64), 256, 0, stream>>>(A, lda, Wl, nsrc, m_buf);
    agg_bn_kernel<<<NN, 128, 0, stream>>>(m_buf, esrc, roff, ndst,
                                          bs + l * HF, gamma + l * HF, beta + l * HF,
                                          rmean + l * HF, rvar + l * HF,
                                          hcat + (size_t)l * HF);
  }
  final_gemm_split<<<dim3((NN + 63) / 64, LL), 256, 0, stream>>>(hcat, linW, part);
  final_reduce<<<(NN * NC / 4 + 255) / 256, 256, 0, stream>>>(part, linb, out);
}